// Round 22
// baseline (88.671 us; speedup 1.0000x reference)
//
#include <hip/hip_runtime.h>
#include <hip/hip_bf16.h>

#define RS 0.9999950000374998f  // 1/sqrt(1+1e-5)

__device__ __forceinline__ float eluf(float x) {
    return x > 0.0f ? x : __expf(x) - 1.0f;
}

typedef __attribute__((ext_vector_type(8))) __bf16 bf16x8;
typedef __attribute__((ext_vector_type(4))) float f32x4;
typedef __attribute__((ext_vector_type(4))) unsigned int u32x4;

// ---------------------------------------------------------------------------
// prep: ONE kernel, block-range split (R17 winner).
//   blocks [0,2048): per-point gather -> pts_local f32 only (PLB removed:
//                    xchain self-gathers); blocks <256 also convert weights.
//   blocks [2048,3072): fts_l = bn(elu(fts @ dense_W + b)) MFMA 128x64, K=64.
// ---------------------------------------------------------------------------
__global__ __launch_bounds__(256) void prep_kernel(
    const float* __restrict__ rep_pts, const float* __restrict__ pts,
    const int* __restrict__ pts_idx, const float* __restrict__ fts,
    const float* __restrict__ d1W, const float* __restrict__ d2W,
    const float* __restrict__ pwW, const float* __restrict__ d2Ws,
    const float* __restrict__ cW, const float* __restrict__ denseW,
    const float* __restrict__ dense_b, const float* __restrict__ dense_g,
    const float* __restrict__ dense_bt, float* __restrict__ pts_local,
    __hip_bfloat16* __restrict__ d1Wt, __hip_bfloat16* __restrict__ d2Wt,
    __hip_bfloat16* __restrict__ pwWt, __hip_bfloat16* __restrict__ d2pWt,
    __hip_bfloat16* __restrict__ cWt, __hip_bfloat16* __restrict__ fts_lB) {
    const int tid = threadIdx.x;
    if (blockIdx.x < 2048) {
        if (blockIdx.x < 256) {
            const int t = blockIdx.x * 256 + tid;
            {
                const int k = t >> 8, n = t & 255;
                d1Wt[n * 256 + k] = __float2bfloat16(d1W[t]);
                d2Wt[n * 256 + k] = __float2bfloat16(d2W[t]);
            }
            if (t < 24576) {
                const int k = t >> 7, n = t & 127;
                pwWt[n * 192 + k] = __float2bfloat16(pwW[t]);
            }
            if (t < 1024) {
                const int q = t >> 5, c = t & 31;
                d2pWt[c * 32 + q] = __float2bfloat16(d2Ws[t]);
            }
            if (t < 16384) {
                const int o = t >> 6, kq = t & 63;
                cWt[t] = (kq < 48) ? __float2bfloat16(cW[o * 48 + kq])
                                   : __float2bfloat16(0.0f);
            }
        }
        const long gp0 = (long)blockIdx.x * 16;
        const int pt = tid >> 4, k = tid & 15;
        const long gp = gp0 + pt;
        const int n = (int)(gp >> 11);
        const int idx = pts_idx[gp * 32 + 2 * k];
        const float* ps = pts + ((long)n * 8192 + idx) * 3;
        const float* rs = rep_pts + gp * 3;
#pragma unroll
        for (int d = 0; d < 3; ++d)
            pts_local[gp * 48 + k * 3 + d] = ps[d] - rs[d];
        return;
    }
    // ---------------- fts_l MFMA tile (128 rows x 64 cols, K=64) ----------
    __shared__ __bf16 As[128][40];
    __shared__ __bf16 Bs[64][40];
    const int w = tid >> 6, l = tid & 63;
    const long row0 = (long)(blockIdx.x - 2048) * 128;
    const int sr = tid >> 1, sh = tid & 1;
    const int fr = l & 15, kg = (l >> 4) * 8;
    f32x4 acc[2][4] = {};
    const float* __restrict__ ap = fts + (row0 + sr) * 64 + sh * 16;
    for (int k0 = 0; k0 < 64; k0 += 32) {
        float av[16];
#pragma unroll
        for (int q = 0; q < 4; ++q) {
            const float4 v = *reinterpret_cast<const float4*>(ap + k0 + q * 4);
            av[q * 4 + 0] = v.x;
            av[q * 4 + 1] = v.y;
            av[q * 4 + 2] = v.z;
            av[q * 4 + 3] = v.w;
        }
        union {
            __bf16 b[16];
            uint4 u[2];
        } cv;
#pragma unroll
        for (int e = 0; e < 16; ++e) cv.b[e] = (__bf16)av[e];
        *reinterpret_cast<uint4*>(&As[sr][sh * 16]) = cv.u[0];
        *reinterpret_cast<uint4*>(&As[sr][sh * 16 + 8]) = cv.u[1];
#pragma unroll
        for (int s = 0; s < 8; ++s) {
            const int e = s * 256 + tid;  // 0..2047
            const int kx = e >> 6, col = e & 63;
            Bs[col][kx] = (__bf16)denseW[(k0 + kx) * 64 + col];
        }
        __syncthreads();
        bf16x8 af[2], bfv[4];
#pragma unroll
        for (int mt = 0; mt < 2; ++mt)
            af[mt] =
                *reinterpret_cast<const bf16x8*>(&As[w * 32 + mt * 16 + fr][kg]);
#pragma unroll
        for (int nt = 0; nt < 4; ++nt)
            bfv[nt] = *reinterpret_cast<const bf16x8*>(&Bs[nt * 16 + fr][kg]);
#pragma unroll
        for (int mt = 0; mt < 2; ++mt)
#pragma unroll
            for (int nt = 0; nt < 4; ++nt)
                acc[mt][nt] = __builtin_amdgcn_mfma_f32_16x16x32_bf16(
                    af[mt], bfv[nt], acc[mt][nt], 0, 0, 0);
        __syncthreads();
    }
    const int rg = (l >> 4) * 4;
#pragma unroll
    for (int nt = 0; nt < 4; ++nt) {
        const int col = nt * 16 + fr;
        const float bb = dense_b[col];
        const float gs = dense_g[col] * RS;
        const float bt = dense_bt[col];
#pragma unroll
        for (int mt = 0; mt < 2; ++mt) {
#pragma unroll
            for (int r = 0; r < 4; ++r) {
                const long row = row0 + w * 32 + mt * 16 + rg + r;
                float v = acc[mt][nt][r] + bb;
                v = eluf(v) * gs + bt;
                fts_lB[row * 64 + col] = __float2bfloat16(v);
            }
        }
    }
}

// ---------------------------------------------------------------------------
// xchain v3: fused Xc -> X1 -> X2, LDS-persistent 64x256 panel; SELF-gathers
// its PL panel (same bf16 rounding as the old PLB relay — proven in R18).
// 512 blocks x 512 threads = 8 waves (2x4; each 32x64). LDS 54.3 KB ->
// 2 blocks/CU so barrier stalls of one block hide under the other.
// ---------------------------------------------------------------------------
__global__ __launch_bounds__(512) void xchain_kernel(
    const float* __restrict__ rep_pts, const float* __restrict__ pts,
    const int* __restrict__ pts_idx, const __hip_bfloat16* __restrict__ cWt,
    const float* __restrict__ cb, const __hip_bfloat16* __restrict__ d1Wt,
    const float* __restrict__ d1b, const __hip_bfloat16* __restrict__ d2Wt,
    const float* __restrict__ d2b, __hip_bfloat16* __restrict__ X2B) {
    __shared__ __bf16 Ap[64][264];
    __shared__ __bf16 Bs[256][40];
    const int tid = threadIdx.x;
    const int w = tid >> 6, l = tid & 63;
    const int wm = w >> 2, wn = w & 3;
    const long row0 = (long)blockIdx.x * 64;
    const int fr = l & 15, kg = (l >> 4) * 8, rg = (l >> 4) * 4;

    // self-gather PL into Ap cols 0..63 (d*16+k layout, 48..63 zero)
    {
        const int r = tid >> 3;        // 0..63
        const int kb = (tid & 7) * 2;  // 2 k's per thread
        const long gp = row0 + r;
        const int n = (int)(gp >> 11);
        const float* rs = rep_pts + gp * 3;
        const float r0 = rs[0], r1 = rs[1], r2 = rs[2];
#pragma unroll
        for (int j = 0; j < 2; ++j) {
            const int k = kb + j;
            const int idx = pts_idx[gp * 32 + 2 * k];
            const float* ps = pts + ((long)n * 8192 + idx) * 3;
            Ap[r][0 * 16 + k] = (__bf16)(ps[0] - r0);
            Ap[r][1 * 16 + k] = (__bf16)(ps[1] - r1);
            Ap[r][2 * 16 + k] = (__bf16)(ps[2] - r2);
            Ap[r][48 + k] = (__bf16)0.0f;
        }
    }
    __syncthreads();

    auto layer = [&](const __hip_bfloat16* __restrict__ Wt,
                     const float* __restrict__ bias, int K, bool act,
                     bool last) {
        f32x4 acc[2][4] = {};
        for (int k0 = 0; k0 < K; k0 += 32) {
#pragma unroll
            for (int s = 0; s < 2; ++s) {
                const int i = s * 512 + tid;
                const int col = i >> 2, q = i & 3;
                *reinterpret_cast<uint4*>(&Bs[col][q * 8]) =
                    *reinterpret_cast<const uint4*>(Wt + (long)col * K + k0 +
                                                    q * 8);
            }
            __syncthreads();
            bf16x8 af[2], bfv[4];
#pragma unroll
            for (int mt = 0; mt < 2; ++mt)
                af[mt] = *reinterpret_cast<const bf16x8*>(
                    &Ap[wm * 32 + mt * 16 + fr][k0 + kg]);
#pragma unroll
            for (int nt = 0; nt < 4; ++nt)
                bfv[nt] = *reinterpret_cast<const bf16x8*>(
                    &Bs[wn * 64 + nt * 16 + fr][kg]);
#pragma unroll
            for (int mt = 0; mt < 2; ++mt)
#pragma unroll
                for (int nt = 0; nt < 4; ++nt)
                    acc[mt][nt] = __builtin_amdgcn_mfma_f32_16x16x32_bf16(
                        af[mt], bfv[nt], acc[mt][nt], 0, 0, 0);
            __syncthreads();
        }
#pragma unroll
        for (int nt = 0; nt < 4; ++nt) {
            const int col = wn * 64 + nt * 16 + fr;
            const float bb = bias[col];
#pragma unroll
            for (int mt = 0; mt < 2; ++mt) {
#pragma unroll
                for (int r = 0; r < 4; ++r) {
                    const int row = wm * 32 + mt * 16 + rg + r;
                    float v = acc[mt][nt][r] + bb;
                    if (act) v = eluf(v);
                    const __bf16 h = (__bf16)v;
                    if (last)
                        X2B[(row0 + row) * 256 + col] =
                            *reinterpret_cast<const __hip_bfloat16*>(&h);
                    else
                        Ap[row][col] = h;
                }
            }
        }
        __syncthreads();
    };

    layer(cWt, cb, 64, true, false);
    layer(d1Wt, d1b, 256, true, false);
    layer(d2Wt, d2b, 256, false, true);
}

// ---------------------------------------------------------------------------
// Final per-point stage v12 (R16/R17 winner, unchanged): weight staging in
// LDS, fcat XOR-swizzle, fused pw GEMM (cross-wave K-split, 3 barriers).
// NOTE: no 2nd launch_bounds arg (R4: clamp -> spill).
// ---------------------------------------------------------------------------
__global__ __launch_bounds__(1024) void final_stage_kernel(
    const __hip_bfloat16* __restrict__ X2B,  // [32768][256] bf16
    const float* __restrict__ pts_local,     // [32768][48] (k*3+d)
    const int* __restrict__ pts_idx,
    const __hip_bfloat16* __restrict__ fts_lB,  // [131072][64] bf16
    const float* __restrict__ d1_W, const float* __restrict__ d1_b,
    const float* __restrict__ d1_g, const float* __restrict__ d1_bt,
    const __hip_bfloat16* __restrict__ d2pWt,  // [32 c][32 q] bf16
    const float* __restrict__ d2_b, const float* __restrict__ d2_g,
    const float* __restrict__ d2_bt, const float* __restrict__ dw_W,
    const float* __restrict__ dw_b,
    const __hip_bfloat16* __restrict__ pwWt,  // [128][192] bf16
    const float* __restrict__ pw_b, const float* __restrict__ sep_g,
    const float* __restrict__ sep_bt,
    float* __restrict__ out)  // [32768][128] f32
{
    __shared__ __bf16 fcatF[16 * 96 * 16];
    __shared__ __bf16 dws[16][200];
    __shared__ float dwT[96][36];
    __shared__ float wd1[6][32];
    __shared__ float d2e[3][32];
    __shared__ float dwbs[192];

    const int tid = threadIdx.x;
    const int w = tid >> 6, l = tid & 63;

    for (int i = tid; i < 3072; i += 1024) dwT[i >> 5][i & 31] = dw_W[i];
    if (tid < 96) wd1[tid >> 5][tid & 31] = d1_W[tid];
    else if (tid < 128) wd1[3][tid & 31] = d1_b[tid & 31];
    else if (tid < 160) wd1[4][tid & 31] = d1_g[tid & 31] * RS;
    else if (tid < 192) wd1[5][tid & 31] = d1_bt[tid & 31];
    else if (tid < 224) d2e[0][tid & 31] = d2_b[tid & 31];
    else if (tid < 256) d2e[1][tid & 31] = d2_g[tid & 31] * RS;
    else if (tid < 288) d2e[2][tid & 31] = d2_bt[tid & 31];
    else if (tid < 480) dwbs[tid - 288] = dw_b[tid - 288];
    __syncthreads();

    const int obid = blockIdx.x;
    const int bid = (obid & 7) * 256 + (obid >> 3);
    const int gp = bid * 16 + w;
    const int ugp = __builtin_amdgcn_readfirstlane(gp);
    const int n = ugp >> 11;
    const int fr = l & 15;
    const int kg = (l >> 4) * 8;
    const int kk = kg & 15;
    const unsigned msk = (l < 32) ? 0xFFFFFFFFu : 0u;
    const int rg4 = (l >> 4) * 4;
    const int colg = (l < 32) ? (32 + l) : (l - 32);
    const __hip_bfloat16* __restrict__ fbase =
        fts_lB + (long)n * 8192 * 64 + colg;

#define FIDX(W, ROW, E) ((((W)*96 + (ROW)) << 4) + ((E) ^ (((ROW)&4) << 1)))

    const int* __restrict__ ip = pts_idx + (long)ugp * 32;
    unsigned fg[16];
#pragma unroll
    for (int j = 0; j < 16; ++j)
        fg[j] = *reinterpret_cast<const unsigned short*>(
            &fbase[(long)ip[2 * j] * 64]);

    const float* __restrict__ pp = pts_local + (long)ugp * 48 + fr * 3;
    const float plA0 = pp[0], plA1 = pp[1], plA2 = pp[2];

    bf16x8 a_l0;
#pragma unroll
    for (int jj = 0; jj < 8; ++jj) {
        const int q = kg + jj;
        float a = wd1[3][q];
        a = fmaf(plA0, wd1[0][q], a);
        a = fmaf(plA1, wd1[1][q], a);
        a = fmaf(plA2, wd1[2][q], a);
        a = eluf(a);
        a = a * wd1[4][q] + wd1[5][q];
        a_l0[jj] = (__bf16)a;
    }

    {
        const bf16x8 b0 =
            *reinterpret_cast<const bf16x8*>(d2pWt + (0 + fr) * 32 + kg);
        const bf16x8 b1 =
            *reinterpret_cast<const bf16x8*>(d2pWt + (16 + fr) * 32 + kg);
        f32x4 lif0 = {}, lif1 = {};
        lif0 = __builtin_amdgcn_mfma_f32_16x16x32_bf16(a_l0, b0, lif0, 0, 0, 0);
        lif1 = __builtin_amdgcn_mfma_f32_16x16x32_bf16(a_l0, b1, lif1, 0, 0, 0);
#pragma unroll
        for (int f = 0; f < 2; ++f) {
            const int c = f * 16 + fr;
            const float bb = d2e[0][c & 31], gs = d2e[1][c & 31],
                        bt = d2e[2][c & 31];
            const f32x4 dd = f ? lif1 : lif0;
            unsigned short pk[4];
#pragma unroll
            for (int r = 0; r < 4; ++r) {
                float v = dd[r] + bb;
                v = eluf(v) * gs + bt;
                const __bf16 h = (__bf16)v;
                pk[r] = *reinterpret_cast<const unsigned short*>(&h);
            }
            *reinterpret_cast<uint2*>(&fcatF[FIDX(w, c, rg4)]) =
                make_uint2((unsigned)pk[0] | ((unsigned)pk[1] << 16),
                           (unsigned)pk[2] | ((unsigned)pk[3] << 16));
        }
    }

    {
        const uint4 lo = make_uint4(fg[0] | (fg[1] << 16), fg[2] | (fg[3] << 16),
                                    fg[4] | (fg[5] << 16), fg[6] | (fg[7] << 16));
        const uint4 hi =
            make_uint4(fg[8] | (fg[9] << 16), fg[10] | (fg[11] << 16),
                       fg[12] | (fg[13] << 16), fg[14] | (fg[15] << 16));
        const int row = 32 + colg;
        *reinterpret_cast<uint4*>(&fcatF[FIDX(w, row, 0)]) = lo;
        *reinterpret_cast<uint4*>(&fcatF[FIDX(w, row, 8)]) = hi;
    }

    u32x4 axu =
        *reinterpret_cast<const u32x4*>(X2B + (long)ugp * 256 + fr * 16 + kk);
    axu &= msk;
    const bf16x8 ax = *reinterpret_cast<const bf16x8*>(&axu);

    f32x4 acc[6];
#pragma unroll
    for (int f = 0; f < 6; ++f) acc[f] = (f32x4){};
#pragma unroll
    for (int f = 0; f < 6; ++f) {
        u32x4 bu =
            *reinterpret_cast<const u32x4*>(&fcatF[FIDX(w, f * 16 + fr, kk)]);
        bu &= msk;
        const bf16x8 bf = *reinterpret_cast<const bf16x8*>(&bu);
        acc[f] = __builtin_amdgcn_mfma_f32_16x16x32_bf16(ax, bf, acc[f], 0, 0, 0);
    }

    float dwv[6][2];
#pragma unroll
    for (int f = 0; f < 6; ++f) {
        const int c = f * 16 + fr;
        const float4 w0 = *reinterpret_cast<const float4*>(&dwT[c][rg4]);
        const float4 w1 = *reinterpret_cast<const float4*>(&dwT[c][16 + rg4]);
        float p0 = acc[f][0] * w0.x;
        p0 = fmaf(acc[f][1], w0.y, p0);
        p0 = fmaf(acc[f][2], w0.z, p0);
        p0 = fmaf(acc[f][3], w0.w, p0);
        float p1 = acc[f][0] * w1.x;
        p1 = fmaf(acc[f][1], w1.y, p1);
        p1 = fmaf(acc[f][2], w1.z, p1);
        p1 = fmaf(acc[f][3], w1.w, p1);
        p0 += __shfl_xor(p0, 16);
        p0 += __shfl_xor(p0, 32);
        p1 += __shfl_xor(p1, 16);
        p1 += __shfl_xor(p1, 32);
        dwv[f][0] = p0;
        dwv[f][1] = p1;
    }
    if (l < 16) {
#pragma unroll
        for (int f = 0; f < 6; ++f) {
            const int c = f * 16 + l;
            __hip_bfloat162 pk;
            pk.x = __float2bfloat16(dwv[f][0] + dwbs[2 * c + 0]);
            pk.y = __float2bfloat16(dwv[f][1] + dwbs[2 * c + 1]);
            *reinterpret_cast<__hip_bfloat162*>(&dws[w][2 * c]) = pk;
        }
    }
    __syncthreads();

    const int c8 = w & 7, h2 = w >> 3;
    f32x4 pacc = {};
#pragma unroll
    for (int t = 0; t < 3; ++t) {
        const int kc = h2 * 3 + t;
        const bf16x8 a =
            *reinterpret_cast<const bf16x8*>(&dws[fr][kc * 32 + kg]);
        const bf16x8 b = *reinterpret_cast<const bf16x8*>(
            pwWt + (long)(c8 * 16 + fr) * 192 + kc * 32 + kg);
        pacc = __builtin_amdgcn_mfma_f32_16x16x32_bf16(a, b, pacc, 0, 0, 0);
    }
    float* red = reinterpret_cast<float*>(fcatF);
    if (w >= 8)
        *reinterpret_cast<f32x4*>(&red[(c8 * 64 + l) * 4]) = pacc;
    __syncthreads();
    if (w < 8) {
        const f32x4 other =
            *reinterpret_cast<const f32x4*>(&red[(c8 * 64 + l) * 4]);
        const int col = c8 * 16 + fr;
        const float bb = pw_b[col];
        const float gs = sep_g[col] * RS;
        const float bt = sep_bt[col];
#pragma unroll
        for (int r = 0; r < 4; ++r) {
            float v = pacc[r] + other[r] + bb;
            v = eluf(v) * gs + bt;
            out[(long)(bid * 16 + rg4 + r) * 128 + col] = v;
        }
    }
#undef FIDX
}

extern "C" void kernel_launch(void* const* d_in, const int* in_sizes, int n_in,
                              void* d_out, int out_size, void* d_ws,
                              size_t ws_size, hipStream_t stream) {
    const float* rep_pts = (const float*)d_in[0];
    const float* pts = (const float*)d_in[1];
    const float* fts = (const float*)d_in[2];
    const int* pts_idx = (const int*)d_in[3];
    const float* dense_W = (const float*)d_in[4];
    const float* dense_b = (const float*)d_in[5];
    const float* dense_g = (const float*)d_in[6];
    const float* dense_bt = (const float*)d_in[7];
    const float* d1_W = (const float*)d_in[8];
    const float* d1_b = (const float*)d_in[9];
    const float* d1_g = (const float*)d_in[10];
    const float* d1_bt = (const float*)d_in[11];
    const float* d2_W = (const float*)d_in[12];
    const float* d2_b = (const float*)d_in[13];
    const float* d2_g = (const float*)d_in[14];
    const float* d2_bt = (const float*)d_in[15];
    const float* xt_cW = (const float*)d_in[16];
    const float* xt_cb = (const float*)d_in[17];
    const float* xt_d1W = (const float*)d_in[18];
    const float* xt_d1b = (const float*)d_in[19];
    const float* xt_d2W = (const float*)d_in[20];
    const float* xt_d2b = (const float*)d_in[21];
    const float* dw_W = (const float*)d_in[22];
    const float* dw_b = (const float*)d_in[23];
    const float* pw_W = (const float*)d_in[24];
    const float* pw_b = (const float*)d_in[25];
    const float* sep_g = (const float*)d_in[26];
    const float* sep_bt = (const float*)d_in[27];

    float* ws = (float*)d_ws;
    __hip_bfloat16* fts_lB = (__hip_bfloat16*)ws;
    __hip_bfloat16* X2Bb = (__hip_bfloat16*)(ws + 8388608);
    float* pl = ws + 25165824;
    __hip_bfloat16* d1Wt = (__hip_bfloat16*)(ws + 26738688);   // 65536
    __hip_bfloat16* d2Wt = (__hip_bfloat16*)(ws + 26771456);   // 65536
    __hip_bfloat16* pwWt = (__hip_bfloat16*)(ws + 26804224);   // 24576
    __hip_bfloat16* d2pWt = (__hip_bfloat16*)(ws + 26816512);  // 1024
    __hip_bfloat16* cWt = (__hip_bfloat16*)(ws + 26819072);    // 16384

    // 1) prep: gather (pts_local only) + weight convert + fts_l
    prep_kernel<<<3072, 256, 0, stream>>>(
        rep_pts, pts, pts_idx, fts, xt_d1W, xt_d2W, pw_W, d2_W, xt_cW, dense_W,
        dense_b, dense_g, dense_bt, pl, d1Wt, d2Wt, pwWt, d2pWt, cWt, fts_lB);

    // 2) xchain: Xc -> X1 -> X2 fused (self-gathered PL; PLB eliminated)
    xchain_kernel<<<512, 512, 0, stream>>>(rep_pts, pts, pts_idx, cWt, xt_cb,
                                           d1Wt, xt_d1b, d2Wt, xt_d2b, X2Bb);

    // 3) final: lifted/gather/fts_X/dw + fused pw -> d_out (f32)
    final_stage_kernel<<<2048, 1024, 0, stream>>>(
        X2Bb, pl, pts_idx, fts_lB, d1_W, d1_b, d1_g, d1_bt, d2pWt, d2_b, d2_g,
        d2_bt, dw_W, dw_b, pwWt, pw_b, sep_g, sep_bt, (float*)d_out);
}

// Round 23
// 87.301 us; speedup vs baseline: 1.0157x; 1.0157x over previous
//
#include <hip/hip_runtime.h>
#include <hip/hip_bf16.h>

#define RS 0.9999950000374998f  // 1/sqrt(1+1e-5)

__device__ __forceinline__ float eluf(float x) {
    return x > 0.0f ? x : __expf(x) - 1.0f;
}

typedef __attribute__((ext_vector_type(8))) __bf16 bf16x8;
typedef __attribute__((ext_vector_type(4))) float f32x4;
typedef __attribute__((ext_vector_type(4))) unsigned int u32x4;

// ---------------------------------------------------------------------------
// prep: ONE kernel, block-range split (R17 winner — LDS union only 15 KB so
// branch coupling is benign).
//   blocks [0,2048): per-point gather (pts_local f32 + PLB bf16) and, on
//                    blocks <256, weight convert (d1/d2/pw/d2p/cW -> bf16^T).
//   blocks [2048,3072): fts_l = bn(elu(fts @ dense_W + b)) MFMA (tile 128x64,
//                    K=64), converting dense_W f32->bf16 inline in staging.
// 256 threads/block.
// ---------------------------------------------------------------------------
__global__ __launch_bounds__(256) void prep_kernel(
    const float* __restrict__ rep_pts, const float* __restrict__ pts,
    const int* __restrict__ pts_idx, const float* __restrict__ fts,
    const float* __restrict__ d1W, const float* __restrict__ d2W,
    const float* __restrict__ pwW, const float* __restrict__ d2Ws,
    const float* __restrict__ cW, const float* __restrict__ denseW,
    const float* __restrict__ dense_b, const float* __restrict__ dense_g,
    const float* __restrict__ dense_bt, float* __restrict__ pts_local,
    __hip_bfloat16* __restrict__ PLB, __hip_bfloat16* __restrict__ d1Wt,
    __hip_bfloat16* __restrict__ d2Wt, __hip_bfloat16* __restrict__ pwWt,
    __hip_bfloat16* __restrict__ d2pWt, __hip_bfloat16* __restrict__ cWt,
    __hip_bfloat16* __restrict__ fts_lB) {
    const int tid = threadIdx.x;
    if (blockIdx.x < 2048) {
        // ---------------- gather (+ convert on first 256 blocks) ----------
        if (blockIdx.x < 256) {
            const int t = blockIdx.x * 256 + tid;
            {
                const int k = t >> 8, n = t & 255;
                d1Wt[n * 256 + k] = __float2bfloat16(d1W[t]);
                d2Wt[n * 256 + k] = __float2bfloat16(d2W[t]);
            }
            if (t < 24576) {
                const int k = t >> 7, n = t & 127;
                pwWt[n * 192 + k] = __float2bfloat16(pwW[t]);
            }
            if (t < 1024) {
                const int q = t >> 5, c = t & 31;
                d2pWt[c * 32 + q] = __float2bfloat16(d2Ws[t]);
            }
            if (t < 16384) {
                const int o = t >> 6, kq = t & 63;
                cWt[t] = (kq < 48) ? __float2bfloat16(cW[o * 48 + kq])
                                   : __float2bfloat16(0.0f);
            }
        }
        const long gp0 = (long)blockIdx.x * 16;
        const int pt = tid >> 4, k = tid & 15;
        const long gp = gp0 + pt;
        const int n = (int)(gp >> 11);
        const int idx = pts_idx[gp * 32 + 2 * k];
        const float* ps = pts + ((long)n * 8192 + idx) * 3;
        const float* rs = rep_pts + gp * 3;
#pragma unroll
        for (int d = 0; d < 3; ++d) {
            const float v = ps[d] - rs[d];
            pts_local[gp * 48 + k * 3 + d] = v;
            PLB[gp * 64 + d * 16 + k] = __float2bfloat16(v);
        }
        PLB[gp * 64 + 48 + k] = __float2bfloat16(0.0f);
        return;
    }
    // ---------------- fts_l MFMA tile (128 rows x 64 cols, K=64) ----------
    __shared__ __bf16 As[128][40];
    __shared__ __bf16 Bs[64][40];
    const int w = tid >> 6, l = tid & 63;
    const long row0 = (long)(blockIdx.x - 2048) * 128;
    const int sr = tid >> 1, sh = tid & 1;
    const int fr = l & 15, kg = (l >> 4) * 8;
    f32x4 acc[2][4] = {};
    const float* __restrict__ ap = fts + (row0 + sr) * 64 + sh * 16;
    for (int k0 = 0; k0 < 64; k0 += 32) {
        float av[16];
#pragma unroll
        for (int q = 0; q < 4; ++q) {
            const float4 v = *reinterpret_cast<const float4*>(ap + k0 + q * 4);
            av[q * 4 + 0] = v.x;
            av[q * 4 + 1] = v.y;
            av[q * 4 + 2] = v.z;
            av[q * 4 + 3] = v.w;
        }
        union {
            __bf16 b[16];
            uint4 u[2];
        } cv;
#pragma unroll
        for (int e = 0; e < 16; ++e) cv.b[e] = (__bf16)av[e];
        *reinterpret_cast<uint4*>(&As[sr][sh * 16]) = cv.u[0];
        *reinterpret_cast<uint4*>(&As[sr][sh * 16 + 8]) = cv.u[1];
        // stage Bs[col][k] = bf16(denseW[(k0+k)*64 + col]) — inline convert
#pragma unroll
        for (int s = 0; s < 8; ++s) {
            const int e = s * 256 + tid;  // 0..2047
            const int kx = e >> 6, col = e & 63;
            Bs[col][kx] = (__bf16)denseW[(k0 + kx) * 64 + col];
        }
        __syncthreads();
        bf16x8 af[2], bfv[4];
#pragma unroll
        for (int mt = 0; mt < 2; ++mt)
            af[mt] =
                *reinterpret_cast<const bf16x8*>(&As[w * 32 + mt * 16 + fr][kg]);
#pragma unroll
        for (int nt = 0; nt < 4; ++nt)
            bfv[nt] = *reinterpret_cast<const bf16x8*>(&Bs[nt * 16 + fr][kg]);
#pragma unroll
        for (int mt = 0; mt < 2; ++mt)
#pragma unroll
            for (int nt = 0; nt < 4; ++nt)
                acc[mt][nt] = __builtin_amdgcn_mfma_f32_16x16x32_bf16(
                    af[mt], bfv[nt], acc[mt][nt], 0, 0, 0);
        __syncthreads();
    }
    const int rg = (l >> 4) * 4;
#pragma unroll
    for (int nt = 0; nt < 4; ++nt) {
        const int col = nt * 16 + fr;
        const float bb = dense_b[col];
        const float gs = dense_g[col] * RS;
        const float bt = dense_bt[col];
#pragma unroll
        for (int mt = 0; mt < 2; ++mt) {
#pragma unroll
            for (int r = 0; r < 4; ++r) {
                const long row = row0 + w * 32 + mt * 16 + rg + r;
                float v = acc[mt][nt][r] + bb;
                v = eluf(v) * gs + bt;
                fts_lB[row * 64 + col] = __float2bfloat16(v);
            }
        }
    }
}

// ---------------------------------------------------------------------------
// xchain v2 (R17 winner): fused Xc -> X1 -> X2, LDS-persistent 64x256 panel.
// 512 blocks x 512 threads = 8 waves (2x4; each 32x64). LDS 54.3 KB ->
// 2 blocks/CU so barrier stalls of one block hide under the other.
// ---------------------------------------------------------------------------
__global__ __launch_bounds__(512) void xchain_kernel(
    const __hip_bfloat16* __restrict__ PLB, const __hip_bfloat16* __restrict__ cWt,
    const float* __restrict__ cb, const __hip_bfloat16* __restrict__ d1Wt,
    const float* __restrict__ d1b, const __hip_bfloat16* __restrict__ d2Wt,
    const float* __restrict__ d2b, __hip_bfloat16* __restrict__ X2B) {
    __shared__ __bf16 Ap[64][264];
    __shared__ __bf16 Bs[256][40];
    const int tid = threadIdx.x;
    const int w = tid >> 6, l = tid & 63;
    const int wm = w >> 2, wn = w & 3;
    const long row0 = (long)blockIdx.x * 64;
    const int fr = l & 15, kg = (l >> 4) * 8, rg = (l >> 4) * 4;

    {
        const int r = tid >> 3, q = tid & 7;
        *reinterpret_cast<uint4*>(&Ap[r][q * 8]) =
            *reinterpret_cast<const uint4*>(PLB + (row0 + r) * 64 + q * 8);
    }
    __syncthreads();

    auto layer = [&](const __hip_bfloat16* __restrict__ Wt,
                     const float* __restrict__ bias, int K, bool act,
                     bool last) {
        f32x4 acc[2][4] = {};
        for (int k0 = 0; k0 < K; k0 += 32) {
#pragma unroll
            for (int s = 0; s < 2; ++s) {
                const int i = s * 512 + tid;
                const int col = i >> 2, q = i & 3;
                *reinterpret_cast<uint4*>(&Bs[col][q * 8]) =
                    *reinterpret_cast<const uint4*>(Wt + (long)col * K + k0 +
                                                    q * 8);
            }
            __syncthreads();
            bf16x8 af[2], bfv[4];
#pragma unroll
            for (int mt = 0; mt < 2; ++mt)
                af[mt] = *reinterpret_cast<const bf16x8*>(
                    &Ap[wm * 32 + mt * 16 + fr][k0 + kg]);
#pragma unroll
            for (int nt = 0; nt < 4; ++nt)
                bfv[nt] = *reinterpret_cast<const bf16x8*>(
                    &Bs[wn * 64 + nt * 16 + fr][kg]);
#pragma unroll
            for (int mt = 0; mt < 2; ++mt)
#pragma unroll
                for (int nt = 0; nt < 4; ++nt)
                    acc[mt][nt] = __builtin_amdgcn_mfma_f32_16x16x32_bf16(
                        af[mt], bfv[nt], acc[mt][nt], 0, 0, 0);
            __syncthreads();
        }
#pragma unroll
        for (int nt = 0; nt < 4; ++nt) {
            const int col = wn * 64 + nt * 16 + fr;
            const float bb = bias[col];
#pragma unroll
            for (int mt = 0; mt < 2; ++mt) {
#pragma unroll
                for (int r = 0; r < 4; ++r) {
                    const int row = wm * 32 + mt * 16 + rg + r;
                    float v = acc[mt][nt][r] + bb;
                    if (act) v = eluf(v);
                    const __bf16 h = (__bf16)v;
                    if (last)
                        X2B[(row0 + row) * 256 + col] =
                            *reinterpret_cast<const __hip_bfloat16*>(&h);
                    else
                        Ap[row][col] = h;
                }
            }
        }
        __syncthreads();
    };

    layer(cWt, cb, 64, true, false);
    layer(d1Wt, d1b, 256, true, false);
    layer(d2Wt, d2b, 256, false, true);
}

// ---------------------------------------------------------------------------
// Final per-point stage v12 (R16/R17 winner): weight staging in LDS, fcat
// XOR-swizzle, fused pw GEMM (cross-wave K-split, 3 barriers) -> d_out f32.
// NOTE: no 2nd launch_bounds arg (R4: clamp -> spill).
// ---------------------------------------------------------------------------
__global__ __launch_bounds__(1024) void final_stage_kernel(
    const __hip_bfloat16* __restrict__ X2B,  // [32768][256] bf16
    const float* __restrict__ pts_local,     // [32768][48] (k*3+d)
    const int* __restrict__ pts_idx,
    const __hip_bfloat16* __restrict__ fts_lB,  // [131072][64] bf16
    const float* __restrict__ d1_W, const float* __restrict__ d1_b,
    const float* __restrict__ d1_g, const float* __restrict__ d1_bt,
    const __hip_bfloat16* __restrict__ d2pWt,  // [32 c][32 q] bf16
    const float* __restrict__ d2_b, const float* __restrict__ d2_g,
    const float* __restrict__ d2_bt, const float* __restrict__ dw_W,
    const float* __restrict__ dw_b,
    const __hip_bfloat16* __restrict__ pwWt,  // [128][192] bf16
    const float* __restrict__ pw_b, const float* __restrict__ sep_g,
    const float* __restrict__ sep_bt,
    float* __restrict__ out)  // [32768][128] f32
{
    __shared__ __bf16 fcatF[16 * 96 * 16];
    __shared__ __bf16 dws[16][200];
    __shared__ float dwT[96][36];
    __shared__ float wd1[6][32];
    __shared__ float d2e[3][32];
    __shared__ float dwbs[192];

    const int tid = threadIdx.x;
    const int w = tid >> 6, l = tid & 63;

    for (int i = tid; i < 3072; i += 1024) dwT[i >> 5][i & 31] = dw_W[i];
    if (tid < 96) wd1[tid >> 5][tid & 31] = d1_W[tid];
    else if (tid < 128) wd1[3][tid & 31] = d1_b[tid & 31];
    else if (tid < 160) wd1[4][tid & 31] = d1_g[tid & 31] * RS;
    else if (tid < 192) wd1[5][tid & 31] = d1_bt[tid & 31];
    else if (tid < 224) d2e[0][tid & 31] = d2_b[tid & 31];
    else if (tid < 256) d2e[1][tid & 31] = d2_g[tid & 31] * RS;
    else if (tid < 288) d2e[2][tid & 31] = d2_bt[tid & 31];
    else if (tid < 480) dwbs[tid - 288] = dw_b[tid - 288];
    __syncthreads();

    const int obid = blockIdx.x;
    const int bid = (obid & 7) * 256 + (obid >> 3);
    const int gp = bid * 16 + w;
    const int ugp = __builtin_amdgcn_readfirstlane(gp);
    const int n = ugp >> 11;
    const int fr = l & 15;
    const int kg = (l >> 4) * 8;
    const int kk = kg & 15;
    const unsigned msk = (l < 32) ? 0xFFFFFFFFu : 0u;
    const int rg4 = (l >> 4) * 4;
    const int colg = (l < 32) ? (32 + l) : (l - 32);
    const __hip_bfloat16* __restrict__ fbase =
        fts_lB + (long)n * 8192 * 64 + colg;

#define FIDX(W, ROW, E) ((((W)*96 + (ROW)) << 4) + ((E) ^ (((ROW)&4) << 1)))

    const int* __restrict__ ip = pts_idx + (long)ugp * 32;
    unsigned fg[16];
#pragma unroll
    for (int j = 0; j < 16; ++j)
        fg[j] = *reinterpret_cast<const unsigned short*>(
            &fbase[(long)ip[2 * j] * 64]);

    const float* __restrict__ pp = pts_local + (long)ugp * 48 + fr * 3;
    const float plA0 = pp[0], plA1 = pp[1], plA2 = pp[2];

    bf16x8 a_l0;
#pragma unroll
    for (int jj = 0; jj < 8; ++jj) {
        const int q = kg + jj;
        float a = wd1[3][q];
        a = fmaf(plA0, wd1[0][q], a);
        a = fmaf(plA1, wd1[1][q], a);
        a = fmaf(plA2, wd1[2][q], a);
        a = eluf(a);
        a = a * wd1[4][q] + wd1[5][q];
        a_l0[jj] = (__bf16)a;
    }

    {
        const bf16x8 b0 =
            *reinterpret_cast<const bf16x8*>(d2pWt + (0 + fr) * 32 + kg);
        const bf16x8 b1 =
            *reinterpret_cast<const bf16x8*>(d2pWt + (16 + fr) * 32 + kg);
        f32x4 lif0 = {}, lif1 = {};
        lif0 = __builtin_amdgcn_mfma_f32_16x16x32_bf16(a_l0, b0, lif0, 0, 0, 0);
        lif1 = __builtin_amdgcn_mfma_f32_16x16x32_bf16(a_l0, b1, lif1, 0, 0, 0);
#pragma unroll
        for (int f = 0; f < 2; ++f) {
            const int c = f * 16 + fr;
            const float bb = d2e[0][c & 31], gs = d2e[1][c & 31],
                        bt = d2e[2][c & 31];
            const f32x4 dd = f ? lif1 : lif0;
            unsigned short pk[4];
#pragma unroll
            for (int r = 0; r < 4; ++r) {
                float v = dd[r] + bb;
                v = eluf(v) * gs + bt;
                const __bf16 h = (__bf16)v;
                pk[r] = *reinterpret_cast<const unsigned short*>(&h);
            }
            *reinterpret_cast<uint2*>(&fcatF[FIDX(w, c, rg4)]) =
                make_uint2((unsigned)pk[0] | ((unsigned)pk[1] << 16),
                           (unsigned)pk[2] | ((unsigned)pk[3] << 16));
        }
    }

    {
        const uint4 lo = make_uint4(fg[0] | (fg[1] << 16), fg[2] | (fg[3] << 16),
                                    fg[4] | (fg[5] << 16), fg[6] | (fg[7] << 16));
        const uint4 hi =
            make_uint4(fg[8] | (fg[9] << 16), fg[10] | (fg[11] << 16),
                       fg[12] | (fg[13] << 16), fg[14] | (fg[15] << 16));
        const int row = 32 + colg;
        *reinterpret_cast<uint4*>(&fcatF[FIDX(w, row, 0)]) = lo;
        *reinterpret_cast<uint4*>(&fcatF[FIDX(w, row, 8)]) = hi;
    }

    u32x4 axu =
        *reinterpret_cast<const u32x4*>(X2B + (long)ugp * 256 + fr * 16 + kk);
    axu &= msk;
    const bf16x8 ax = *reinterpret_cast<const bf16x8*>(&axu);

    f32x4 acc[6];
#pragma unroll
    for (int f = 0; f < 6; ++f) acc[f] = (f32x4){};
#pragma unroll
    for (int f = 0; f < 6; ++f) {
        u32x4 bu =
            *reinterpret_cast<const u32x4*>(&fcatF[FIDX(w, f * 16 + fr, kk)]);
        bu &= msk;
        const bf16x8 bf = *reinterpret_cast<const bf16x8*>(&bu);
        acc[f] = __builtin_amdgcn_mfma_f32_16x16x32_bf16(ax, bf, acc[f], 0, 0, 0);
    }

    float dwv[6][2];
#pragma unroll
    for (int f = 0; f < 6; ++f) {
        const int c = f * 16 + fr;
        const float4 w0 = *reinterpret_cast<const float4*>(&dwT[c][rg4]);
        const float4 w1 = *reinterpret_cast<const float4*>(&dwT[c][16 + rg4]);
        float p0 = acc[f][0] * w0.x;
        p0 = fmaf(acc[f][1], w0.y, p0);
        p0 = fmaf(acc[f][2], w0.z, p0);
        p0 = fmaf(acc[f][3], w0.w, p0);
        float p1 = acc[f][0] * w1.x;
        p1 = fmaf(acc[f][1], w1.y, p1);
        p1 = fmaf(acc[f][2], w1.z, p1);
        p1 = fmaf(acc[f][3], w1.w, p1);
        p0 += __shfl_xor(p0, 16);
        p0 += __shfl_xor(p0, 32);
        p1 += __shfl_xor(p1, 16);
        p1 += __shfl_xor(p1, 32);
        dwv[f][0] = p0;
        dwv[f][1] = p1;
    }
    if (l < 16) {
#pragma unroll
        for (int f = 0; f < 6; ++f) {
            const int c = f * 16 + l;
            __hip_bfloat162 pk;
            pk.x = __float2bfloat16(dwv[f][0] + dwbs[2 * c + 0]);
            pk.y = __float2bfloat16(dwv[f][1] + dwbs[2 * c + 1]);
            *reinterpret_cast<__hip_bfloat162*>(&dws[w][2 * c]) = pk;
        }
    }
    __syncthreads();

    const int c8 = w & 7, h2 = w >> 3;
    f32x4 pacc = {};
#pragma unroll
    for (int t = 0; t < 3; ++t) {
        const int kc = h2 * 3 + t;
        const bf16x8 a =
            *reinterpret_cast<const bf16x8*>(&dws[fr][kc * 32 + kg]);
        const bf16x8 b = *reinterpret_cast<const bf16x8*>(
            pwWt + (long)(c8 * 16 + fr) * 192 + kc * 32 + kg);
        pacc = __builtin_amdgcn_mfma_f32_16x16x32_bf16(a, b, pacc, 0, 0, 0);
    }
    float* red = reinterpret_cast<float*>(fcatF);
    if (w >= 8)
        *reinterpret_cast<f32x4*>(&red[(c8 * 64 + l) * 4]) = pacc;
    __syncthreads();
    if (w < 8) {
        const f32x4 other =
            *reinterpret_cast<const f32x4*>(&red[(c8 * 64 + l) * 4]);
        const int col = c8 * 16 + fr;
        const float bb = pw_b[col];
        const float gs = sep_g[col] * RS;
        const float bt = sep_bt[col];
#pragma unroll
        for (int r = 0; r < 4; ++r) {
            float v = pacc[r] + other[r] + bb;
            v = eluf(v) * gs + bt;
            out[(long)(bid * 16 + rg4 + r) * 128 + col] = v;
        }
    }
#undef FIDX
}

extern "C" void kernel_launch(void* const* d_in, const int* in_sizes, int n_in,
                              void* d_out, int out_size, void* d_ws,
                              size_t ws_size, hipStream_t stream) {
    const float* rep_pts = (const float*)d_in[0];
    const float* pts = (const float*)d_in[1];
    const float* fts = (const float*)d_in[2];
    const int* pts_idx = (const int*)d_in[3];
    const float* dense_W = (const float*)d_in[4];
    const float* dense_b = (const float*)d_in[5];
    const float* dense_g = (const float*)d_in[6];
    const float* dense_bt = (const float*)d_in[7];
    const float* d1_W = (const float*)d_in[8];
    const float* d1_b = (const float*)d_in[9];
    const float* d1_g = (const float*)d_in[10];
    const float* d1_bt = (const float*)d_in[11];
    const float* d2_W = (const float*)d_in[12];
    const float* d2_b = (const float*)d_in[13];
    const float* d2_g = (const float*)d_in[14];
    const float* d2_bt = (const float*)d_in[15];
    const float* xt_cW = (const float*)d_in[16];
    const float* xt_cb = (const float*)d_in[17];
    const float* xt_d1W = (const float*)d_in[18];
    const float* xt_d1b = (const float*)d_in[19];
    const float* xt_d2W = (const float*)d_in[20];
    const float* xt_d2b = (const float*)d_in[21];
    const float* dw_W = (const float*)d_in[22];
    const float* dw_b = (const float*)d_in[23];
    const float* pw_W = (const float*)d_in[24];
    const float* pw_b = (const float*)d_in[25];
    const float* sep_g = (const float*)d_in[26];
    const float* sep_bt = (const float*)d_in[27];

    float* ws = (float*)d_ws;
    __hip_bfloat16* fts_lB = (__hip_bfloat16*)ws;
    __hip_bfloat16* X2Bb = (__hip_bfloat16*)(ws + 8388608);
    __hip_bfloat16* PLB = (__hip_bfloat16*)(ws + 20971520);
    float* pl = ws + 25165824;
    __hip_bfloat16* d1Wt = (__hip_bfloat16*)(ws + 26738688);   // 65536
    __hip_bfloat16* d2Wt = (__hip_bfloat16*)(ws + 26771456);   // 65536
    __hip_bfloat16* pwWt = (__hip_bfloat16*)(ws + 26804224);   // 24576
    __hip_bfloat16* d2pWt = (__hip_bfloat16*)(ws + 26816512);  // 1024
    __hip_bfloat16* cWt = (__hip_bfloat16*)(ws + 26819072);    // 16384

    // 1) prep: gather + weight convert + fts_l (merged, block-range split)
    prep_kernel<<<3072, 256, 0, stream>>>(
        rep_pts, pts, pts_idx, fts, xt_d1W, xt_d2W, pw_W, d2_W, xt_cW, dense_W,
        dense_b, dense_g, dense_bt, pl, PLB, d1Wt, d2Wt, pwWt, d2pWt, cWt,
        fts_lB);

    // 2) xchain: Xc -> X1 -> X2 fused (64-row panels, 2 blocks/CU)
    xchain_kernel<<<512, 512, 0, stream>>>(PLB, cWt, xt_cb, d1Wt, xt_d1b, d2Wt,
                                           xt_d2b, X2Bb);

    // 3) final: lifted/gather/fts_X/dw + fused pw -> d_out (f32)
    final_stage_kernel<<<2048, 1024, 0, stream>>>(
        X2Bb, pl, pts_idx, fts_lB, d1_W, d1_b, d1_g, d1_bt, d2pWt, d2_b, d2_g,
        d2_bt, dw_W, dw_b, pwWt, pw_b, sep_g, sep_bt, (float*)d_out);
}

// Round 24
// 86.529 us; speedup vs baseline: 1.0248x; 1.0089x over previous
//
#include <hip/hip_runtime.h>
#include <hip/hip_bf16.h>

#define RS 0.9999950000374998f  // 1/sqrt(1+1e-5)

__device__ __forceinline__ float eluf(float x) {
    return x > 0.0f ? x : __expf(x) - 1.0f;
}

typedef __attribute__((ext_vector_type(8))) __bf16 bf16x8;
typedef __attribute__((ext_vector_type(4))) float f32x4;
typedef __attribute__((ext_vector_type(4))) unsigned int u32x4;

// ---------------------------------------------------------------------------
// prep: ONE kernel, block-range split (R17 winner — LDS union only 15 KB so
// branch coupling is benign).
//   blocks [0,2048): per-point gather (pts_local f32 + PLB bf16) and, on
//                    blocks <256, weight convert (d1/d2/pw/d2p/cW -> bf16^T).
//   blocks [2048,3072): fts_l = bn(elu(fts @ dense_W + b)) MFMA (tile 128x64,
//                    K=64), converting dense_W f32->bf16 inline in staging.
// 256 threads/block.
// ---------------------------------------------------------------------------
__global__ __launch_bounds__(256) void prep_kernel(
    const float* __restrict__ rep_pts, const float* __restrict__ pts,
    const int* __restrict__ pts_idx, const float* __restrict__ fts,
    const float* __restrict__ d1W, const float* __restrict__ d2W,
    const float* __restrict__ pwW, const float* __restrict__ d2Ws,
    const float* __restrict__ cW, const float* __restrict__ denseW,
    const float* __restrict__ dense_b, const float* __restrict__ dense_g,
    const float* __restrict__ dense_bt, float* __restrict__ pts_local,
    __hip_bfloat16* __restrict__ PLB, __hip_bfloat16* __restrict__ d1Wt,
    __hip_bfloat16* __restrict__ d2Wt, __hip_bfloat16* __restrict__ pwWt,
    __hip_bfloat16* __restrict__ d2pWt, __hip_bfloat16* __restrict__ cWt,
    __hip_bfloat16* __restrict__ fts_lB) {
    const int tid = threadIdx.x;
    if (blockIdx.x < 2048) {
        // ---------------- gather (+ convert on first 256 blocks) ----------
        if (blockIdx.x < 256) {
            const int t = blockIdx.x * 256 + tid;
            {
                const int k = t >> 8, n = t & 255;
                d1Wt[n * 256 + k] = __float2bfloat16(d1W[t]);
                d2Wt[n * 256 + k] = __float2bfloat16(d2W[t]);
            }
            if (t < 24576) {
                const int k = t >> 7, n = t & 127;
                pwWt[n * 192 + k] = __float2bfloat16(pwW[t]);
            }
            if (t < 1024) {
                const int q = t >> 5, c = t & 31;
                d2pWt[c * 32 + q] = __float2bfloat16(d2Ws[t]);
            }
            if (t < 16384) {
                const int o = t >> 6, kq = t & 63;
                cWt[t] = (kq < 48) ? __float2bfloat16(cW[o * 48 + kq])
                                   : __float2bfloat16(0.0f);
            }
        }
        const long gp0 = (long)blockIdx.x * 16;
        const int pt = tid >> 4, k = tid & 15;
        const long gp = gp0 + pt;
        const int n = (int)(gp >> 11);
        const int idx = pts_idx[gp * 32 + 2 * k];
        const float* ps = pts + ((long)n * 8192 + idx) * 3;
        const float* rs = rep_pts + gp * 3;
#pragma unroll
        for (int d = 0; d < 3; ++d) {
            const float v = ps[d] - rs[d];
            pts_local[gp * 48 + k * 3 + d] = v;
            PLB[gp * 64 + d * 16 + k] = __float2bfloat16(v);
        }
        PLB[gp * 64 + 48 + k] = __float2bfloat16(0.0f);
        return;
    }
    // ---------------- fts_l MFMA tile (128 rows x 64 cols, K=64) ----------
    __shared__ __bf16 As[128][40];
    __shared__ __bf16 Bs[64][40];
    const int w = tid >> 6, l = tid & 63;
    const long row0 = (long)(blockIdx.x - 2048) * 128;
    const int sr = tid >> 1, sh = tid & 1;
    const int fr = l & 15, kg = (l >> 4) * 8;
    f32x4 acc[2][4] = {};
    const float* __restrict__ ap = fts + (row0 + sr) * 64 + sh * 16;
    for (int k0 = 0; k0 < 64; k0 += 32) {
        float av[16];
#pragma unroll
        for (int q = 0; q < 4; ++q) {
            const float4 v = *reinterpret_cast<const float4*>(ap + k0 + q * 4);
            av[q * 4 + 0] = v.x;
            av[q * 4 + 1] = v.y;
            av[q * 4 + 2] = v.z;
            av[q * 4 + 3] = v.w;
        }
        union {
            __bf16 b[16];
            uint4 u[2];
        } cv;
#pragma unroll
        for (int e = 0; e < 16; ++e) cv.b[e] = (__bf16)av[e];
        *reinterpret_cast<uint4*>(&As[sr][sh * 16]) = cv.u[0];
        *reinterpret_cast<uint4*>(&As[sr][sh * 16 + 8]) = cv.u[1];
        // stage Bs[col][k] = bf16(denseW[(k0+k)*64 + col]) — inline convert
#pragma unroll
        for (int s = 0; s < 8; ++s) {
            const int e = s * 256 + tid;  // 0..2047
            const int kx = e >> 6, col = e & 63;
            Bs[col][kx] = (__bf16)denseW[(k0 + kx) * 64 + col];
        }
        __syncthreads();
        bf16x8 af[2], bfv[4];
#pragma unroll
        for (int mt = 0; mt < 2; ++mt)
            af[mt] =
                *reinterpret_cast<const bf16x8*>(&As[w * 32 + mt * 16 + fr][kg]);
#pragma unroll
        for (int nt = 0; nt < 4; ++nt)
            bfv[nt] = *reinterpret_cast<const bf16x8*>(&Bs[nt * 16 + fr][kg]);
#pragma unroll
        for (int mt = 0; mt < 2; ++mt)
#pragma unroll
            for (int nt = 0; nt < 4; ++nt)
                acc[mt][nt] = __builtin_amdgcn_mfma_f32_16x16x32_bf16(
                    af[mt], bfv[nt], acc[mt][nt], 0, 0, 0);
        __syncthreads();
    }
    const int rg = (l >> 4) * 4;
#pragma unroll
    for (int nt = 0; nt < 4; ++nt) {
        const int col = nt * 16 + fr;
        const float bb = dense_b[col];
        const float gs = dense_g[col] * RS;
        const float bt = dense_bt[col];
#pragma unroll
        for (int mt = 0; mt < 2; ++mt) {
#pragma unroll
            for (int r = 0; r < 4; ++r) {
                const long row = row0 + w * 32 + mt * 16 + rg + r;
                float v = acc[mt][nt][r] + bb;
                v = eluf(v) * gs + bt;
                fts_lB[row * 64 + col] = __float2bfloat16(v);
            }
        }
    }
}

// ---------------------------------------------------------------------------
// xchain v2 (R17 winner): fused Xc -> X1 -> X2, LDS-persistent 64x256 panel.
// 512 blocks x 512 threads = 8 waves (2x4; each 32x64). LDS 54.3 KB ->
// 2 blocks/CU so barrier stalls of one block hide under the other.
// ---------------------------------------------------------------------------
__global__ __launch_bounds__(512) void xchain_kernel(
    const __hip_bfloat16* __restrict__ PLB, const __hip_bfloat16* __restrict__ cWt,
    const float* __restrict__ cb, const __hip_bfloat16* __restrict__ d1Wt,
    const float* __restrict__ d1b, const __hip_bfloat16* __restrict__ d2Wt,
    const float* __restrict__ d2b, __hip_bfloat16* __restrict__ X2B) {
    __shared__ __bf16 Ap[64][264];
    __shared__ __bf16 Bs[256][40];
    const int tid = threadIdx.x;
    const int w = tid >> 6, l = tid & 63;
    const int wm = w >> 2, wn = w & 3;
    const long row0 = (long)blockIdx.x * 64;
    const int fr = l & 15, kg = (l >> 4) * 8, rg = (l >> 4) * 4;

    {
        const int r = tid >> 3, q = tid & 7;
        *reinterpret_cast<uint4*>(&Ap[r][q * 8]) =
            *reinterpret_cast<const uint4*>(PLB + (row0 + r) * 64 + q * 8);
    }
    __syncthreads();

    auto layer = [&](const __hip_bfloat16* __restrict__ Wt,
                     const float* __restrict__ bias, int K, bool act,
                     bool last) {
        f32x4 acc[2][4] = {};
        for (int k0 = 0; k0 < K; k0 += 32) {
#pragma unroll
            for (int s = 0; s < 2; ++s) {
                const int i = s * 512 + tid;
                const int col = i >> 2, q = i & 3;
                *reinterpret_cast<uint4*>(&Bs[col][q * 8]) =
                    *reinterpret_cast<const uint4*>(Wt + (long)col * K + k0 +
                                                    q * 8);
            }
            __syncthreads();
            bf16x8 af[2], bfv[4];
#pragma unroll
            for (int mt = 0; mt < 2; ++mt)
                af[mt] = *reinterpret_cast<const bf16x8*>(
                    &Ap[wm * 32 + mt * 16 + fr][k0 + kg]);
#pragma unroll
            for (int nt = 0; nt < 4; ++nt)
                bfv[nt] = *reinterpret_cast<const bf16x8*>(
                    &Bs[wn * 64 + nt * 16 + fr][kg]);
#pragma unroll
            for (int mt = 0; mt < 2; ++mt)
#pragma unroll
                for (int nt = 0; nt < 4; ++nt)
                    acc[mt][nt] = __builtin_amdgcn_mfma_f32_16x16x32_bf16(
                        af[mt], bfv[nt], acc[mt][nt], 0, 0, 0);
            __syncthreads();
        }
#pragma unroll
        for (int nt = 0; nt < 4; ++nt) {
            const int col = wn * 64 + nt * 16 + fr;
            const float bb = bias[col];
#pragma unroll
            for (int mt = 0; mt < 2; ++mt) {
#pragma unroll
                for (int r = 0; r < 4; ++r) {
                    const int row = wm * 32 + mt * 16 + rg + r;
                    float v = acc[mt][nt][r] + bb;
                    if (act) v = eluf(v);
                    const __bf16 h = (__bf16)v;
                    if (last)
                        X2B[(row0 + row) * 256 + col] =
                            *reinterpret_cast<const __hip_bfloat16*>(&h);
                    else
                        Ap[row][col] = h;
                }
            }
        }
        __syncthreads();
    };

    layer(cWt, cb, 64, true, false);
    layer(d1Wt, d1b, 256, true, false);
    layer(d2Wt, d2b, 256, false, true);
}

// ---------------------------------------------------------------------------
// Final per-point stage v14: v12 + gather/X2B/pts_local loads HOISTED above
// the weight-staging barrier (they are independent of staged LDS weights, so
// their ~700-1000 cy latency hides under the staging stores + rendezvous).
// +~22 VGPR live across staging; LDS (2 blocks/CU = 8 waves/SIMD) remains the
// binding occupancy limit so no residency loss. Bit-identical arithmetic.
// NOTE: no 2nd launch_bounds arg (R4: clamp -> spill).
// ---------------------------------------------------------------------------
__global__ __launch_bounds__(1024) void final_stage_kernel(
    const __hip_bfloat16* __restrict__ X2B,  // [32768][256] bf16
    const float* __restrict__ pts_local,     // [32768][48] (k*3+d)
    const int* __restrict__ pts_idx,
    const __hip_bfloat16* __restrict__ fts_lB,  // [131072][64] bf16
    const float* __restrict__ d1_W, const float* __restrict__ d1_b,
    const float* __restrict__ d1_g, const float* __restrict__ d1_bt,
    const __hip_bfloat16* __restrict__ d2pWt,  // [32 c][32 q] bf16
    const float* __restrict__ d2_b, const float* __restrict__ d2_g,
    const float* __restrict__ d2_bt, const float* __restrict__ dw_W,
    const float* __restrict__ dw_b,
    const __hip_bfloat16* __restrict__ pwWt,  // [128][192] bf16
    const float* __restrict__ pw_b, const float* __restrict__ sep_g,
    const float* __restrict__ sep_bt,
    float* __restrict__ out)  // [32768][128] f32
{
    __shared__ __bf16 fcatF[16 * 96 * 16];
    __shared__ __bf16 dws[16][200];
    __shared__ float dwT[96][36];
    __shared__ float wd1[6][32];
    __shared__ float d2e[3][32];
    __shared__ float dwbs[192];

    const int tid = threadIdx.x;
    const int w = tid >> 6, l = tid & 63;

    // ---- indices (pure arithmetic) ----
    const int obid = blockIdx.x;
    const int bid = (obid & 7) * 256 + (obid >> 3);  // bijective, 2048%8==0
    const int gp = bid * 16 + w;
    const int ugp = __builtin_amdgcn_readfirstlane(gp);
    const int n = ugp >> 11;
    const int fr = l & 15;
    const int kg = (l >> 4) * 8;
    const int kk = kg & 15;
    const unsigned msk = (l < 32) ? 0xFFFFFFFFu : 0u;
    const int rg4 = (l >> 4) * 4;
    const int colg = (l < 32) ? (32 + l) : (l - 32);
    const __hip_bfloat16* __restrict__ fbase =
        fts_lB + (long)n * 8192 * 64 + colg;

    // ---- HOISTED independent global loads (issue before staging) ----
    const int* __restrict__ ip = pts_idx + (long)ugp * 32;
    unsigned fg[16];
#pragma unroll
    for (int j = 0; j < 16; ++j)
        fg[j] = *reinterpret_cast<const unsigned short*>(
            &fbase[(long)ip[2 * j] * 64]);
    const float* __restrict__ pp = pts_local + (long)ugp * 48 + fr * 3;
    const float plA0 = pp[0], plA1 = pp[1], plA2 = pp[2];
    u32x4 axu =
        *reinterpret_cast<const u32x4*>(X2B + (long)ugp * 256 + fr * 16 + kk);

    // ---- block-level weight staging (barrier 1) ----
    for (int i = tid; i < 3072; i += 1024) dwT[i >> 5][i & 31] = dw_W[i];
    if (tid < 96) wd1[tid >> 5][tid & 31] = d1_W[tid];
    else if (tid < 128) wd1[3][tid & 31] = d1_b[tid & 31];
    else if (tid < 160) wd1[4][tid & 31] = d1_g[tid & 31] * RS;
    else if (tid < 192) wd1[5][tid & 31] = d1_bt[tid & 31];
    else if (tid < 224) d2e[0][tid & 31] = d2_b[tid & 31];
    else if (tid < 256) d2e[1][tid & 31] = d2_g[tid & 31] * RS;
    else if (tid < 288) d2e[2][tid & 31] = d2_bt[tid & 31];
    else if (tid < 480) dwbs[tid - 288] = dw_b[tid - 288];
    __syncthreads();

#define FIDX(W, ROW, E) ((((W)*96 + (ROW)) << 4) + ((E) ^ (((ROW)&4) << 1)))

    // ---- l0 row-owner A-frag ----
    bf16x8 a_l0;
#pragma unroll
    for (int jj = 0; jj < 8; ++jj) {
        const int q = kg + jj;
        float a = wd1[3][q];
        a = fmaf(plA0, wd1[0][q], a);
        a = fmaf(plA1, wd1[1][q], a);
        a = fmaf(plA2, wd1[2][q], a);
        a = eluf(a);
        a = a * wd1[4][q] + wd1[5][q];
        a_l0[jj] = (__bf16)a;
    }

    // ---- lifted = l0 @ d2_W via 2 MFMA -> fcat cols 0..31 ----
    {
        const bf16x8 b0 =
            *reinterpret_cast<const bf16x8*>(d2pWt + (0 + fr) * 32 + kg);
        const bf16x8 b1 =
            *reinterpret_cast<const bf16x8*>(d2pWt + (16 + fr) * 32 + kg);
        f32x4 lif0 = {}, lif1 = {};
        lif0 = __builtin_amdgcn_mfma_f32_16x16x32_bf16(a_l0, b0, lif0, 0, 0, 0);
        lif1 = __builtin_amdgcn_mfma_f32_16x16x32_bf16(a_l0, b1, lif1, 0, 0, 0);
#pragma unroll
        for (int f = 0; f < 2; ++f) {
            const int c = f * 16 + fr;
            const float bb = d2e[0][c & 31], gs = d2e[1][c & 31],
                        bt = d2e[2][c & 31];
            const f32x4 dd = f ? lif1 : lif0;
            unsigned short pk[4];
#pragma unroll
            for (int r = 0; r < 4; ++r) {
                float v = dd[r] + bb;
                v = eluf(v) * gs + bt;
                const __bf16 h = (__bf16)v;
                pk[r] = *reinterpret_cast<const unsigned short*>(&h);
            }
            *reinterpret_cast<uint2*>(&fcatF[FIDX(w, c, rg4)]) =
                make_uint2((unsigned)pk[0] | ((unsigned)pk[1] << 16),
                           (unsigned)pk[2] | ((unsigned)pk[3] << 16));
        }
    }

    // ---- fg (bf16 bits, preloaded) -> fcat[32+colg][0..15] ----
    {
        const uint4 lo = make_uint4(fg[0] | (fg[1] << 16), fg[2] | (fg[3] << 16),
                                    fg[4] | (fg[5] << 16), fg[6] | (fg[7] << 16));
        const uint4 hi =
            make_uint4(fg[8] | (fg[9] << 16), fg[10] | (fg[11] << 16),
                       fg[12] | (fg[13] << 16), fg[14] | (fg[15] << 16));
        const int row = 32 + colg;
        *reinterpret_cast<uint4*>(&fcatF[FIDX(w, row, 0)]) = lo;
        *reinterpret_cast<uint4*>(&fcatF[FIDX(w, row, 8)]) = hi;
    }

    // ---- A-frag: X row fr (preloaded; zero k>=16 half via mask) ----
    axu &= msk;
    const bf16x8 ax = *reinterpret_cast<const bf16x8*>(&axu);

    // ---- fts_X: 6 B-frags from fcat + 6 MFMA ----
    f32x4 acc[6];
#pragma unroll
    for (int f = 0; f < 6; ++f) acc[f] = (f32x4){};
#pragma unroll
    for (int f = 0; f < 6; ++f) {
        u32x4 bu =
            *reinterpret_cast<const u32x4*>(&fcatF[FIDX(w, f * 16 + fr, kk)]);
        bu &= msk;
        const bf16x8 bf = *reinterpret_cast<const bf16x8*>(&bu);
        acc[f] = __builtin_amdgcn_mfma_f32_16x16x32_bf16(ax, bf, acc[f], 0, 0, 0);
    }

    // ---- dw: partials rows rg4..rg4+3, butterfly ----
    float dwv[6][2];
#pragma unroll
    for (int f = 0; f < 6; ++f) {
        const int c = f * 16 + fr;
        const float4 w0 = *reinterpret_cast<const float4*>(&dwT[c][rg4]);
        const float4 w1 = *reinterpret_cast<const float4*>(&dwT[c][16 + rg4]);
        float p0 = acc[f][0] * w0.x;
        p0 = fmaf(acc[f][1], w0.y, p0);
        p0 = fmaf(acc[f][2], w0.z, p0);
        p0 = fmaf(acc[f][3], w0.w, p0);
        float p1 = acc[f][0] * w1.x;
        p1 = fmaf(acc[f][1], w1.y, p1);
        p1 = fmaf(acc[f][2], w1.z, p1);
        p1 = fmaf(acc[f][3], w1.w, p1);
        p0 += __shfl_xor(p0, 16);
        p0 += __shfl_xor(p0, 32);
        p1 += __shfl_xor(p1, 16);
        p1 += __shfl_xor(p1, 32);
        dwv[f][0] = p0;
        dwv[f][1] = p1;
    }
    if (l < 16) {
#pragma unroll
        for (int f = 0; f < 6; ++f) {
            const int c = f * 16 + l;
            __hip_bfloat162 pk;
            pk.x = __float2bfloat16(dwv[f][0] + dwbs[2 * c + 0]);
            pk.y = __float2bfloat16(dwv[f][1] + dwbs[2 * c + 1]);
            *reinterpret_cast<__hip_bfloat162*>(&dws[w][2 * c]) = pk;
        }
    }
    __syncthreads();  // barrier 2: dws complete; fcat reads all done

    // ---- fused pw (cross-wave K-split, barrier 3) ----
    const int c8 = w & 7, h2 = w >> 3;
    f32x4 pacc = {};
#pragma unroll
    for (int t = 0; t < 3; ++t) {
        const int kc = h2 * 3 + t;
        const bf16x8 a =
            *reinterpret_cast<const bf16x8*>(&dws[fr][kc * 32 + kg]);
        const bf16x8 b = *reinterpret_cast<const bf16x8*>(
            pwWt + (long)(c8 * 16 + fr) * 192 + kc * 32 + kg);
        pacc = __builtin_amdgcn_mfma_f32_16x16x32_bf16(a, b, pacc, 0, 0, 0);
    }
    float* red = reinterpret_cast<float*>(fcatF);
    if (w >= 8)
        *reinterpret_cast<f32x4*>(&red[(c8 * 64 + l) * 4]) = pacc;
    __syncthreads();
    if (w < 8) {
        const f32x4 other =
            *reinterpret_cast<const f32x4*>(&red[(c8 * 64 + l) * 4]);
        const int col = c8 * 16 + fr;
        const float bb = pw_b[col];
        const float gs = sep_g[col] * RS;
        const float bt = sep_bt[col];
#pragma unroll
        for (int r = 0; r < 4; ++r) {
            float v = pacc[r] + other[r] + bb;
            v = eluf(v) * gs + bt;
            out[(long)(bid * 16 + rg4 + r) * 128 + col] = v;
        }
    }
#undef FIDX
}

extern "C" void kernel_launch(void* const* d_in, const int* in_sizes, int n_in,
                              void* d_out, int out_size, void* d_ws,
                              size_t ws_size, hipStream_t stream) {
    const float* rep_pts = (const float*)d_in[0];
    const float* pts = (const float*)d_in[1];
    const float* fts = (const float*)d_in[2];
    const int* pts_idx = (const int*)d_in[3];
    const float* dense_W = (const float*)d_in[4];
    const float* dense_b = (const float*)d_in[5];
    const float* dense_g = (const float*)d_in[6];
    const float* dense_bt = (const float*)d_in[7];
    const float* d1_W = (const float*)d_in[8];
    const float* d1_b = (const float*)d_in[9];
    const float* d1_g = (const float*)d_in[10];
    const float* d1_bt = (const float*)d_in[11];
    const float* d2_W = (const float*)d_in[12];
    const float* d2_b = (const float*)d_in[13];
    const float* d2_g = (const float*)d_in[14];
    const float* d2_bt = (const float*)d_in[15];
    const float* xt_cW = (const float*)d_in[16];
    const float* xt_cb = (const float*)d_in[17];
    const float* xt_d1W = (const float*)d_in[18];
    const float* xt_d1b = (const float*)d_in[19];
    const float* xt_d2W = (const float*)d_in[20];
    const float* xt_d2b = (const float*)d_in[21];
    const float* dw_W = (const float*)d_in[22];
    const float* dw_b = (const float*)d_in[23];
    const float* pw_W = (const float*)d_in[24];
    const float* pw_b = (const float*)d_in[25];
    const float* sep_g = (const float*)d_in[26];
    const float* sep_bt = (const float*)d_in[27];

    float* ws = (float*)d_ws;
    __hip_bfloat16* fts_lB = (__hip_bfloat16*)ws;
    __hip_bfloat16* X2Bb = (__hip_bfloat16*)(ws + 8388608);
    __hip_bfloat16* PLB = (__hip_bfloat16*)(ws + 20971520);
    float* pl = ws + 25165824;
    __hip_bfloat16* d1Wt = (__hip_bfloat16*)(ws + 26738688);   // 65536
    __hip_bfloat16* d2Wt = (__hip_bfloat16*)(ws + 26771456);   // 65536
    __hip_bfloat16* pwWt = (__hip_bfloat16*)(ws + 26804224);   // 24576
    __hip_bfloat16* d2pWt = (__hip_bfloat16*)(ws + 26816512);  // 1024
    __hip_bfloat16* cWt = (__hip_bfloat16*)(ws + 26819072);    // 16384

    // 1) prep: gather + weight convert + fts_l (merged, block-range split)
    prep_kernel<<<3072, 256, 0, stream>>>(
        rep_pts, pts, pts_idx, fts, xt_d1W, xt_d2W, pw_W, d2_W, xt_cW, dense_W,
        dense_b, dense_g, dense_bt, pl, PLB, d1Wt, d2Wt, pwWt, d2pWt, cWt,
        fts_lB);

    // 2) xchain: Xc -> X1 -> X2 fused (64-row panels, 2 blocks/CU)
    xchain_kernel<<<512, 512, 0, stream>>>(PLB, cWt, xt_cb, d1Wt, xt_d1b, d2Wt,
                                           xt_d2b, X2Bb);

    // 3) final: lifted/gather/fts_X/dw + fused pw -> d_out (f32)
    final_stage_kernel<<<2048, 1024, 0, stream>>>(
        X2Bb, pl, pts_idx, fts_lB, d1_W, d1_b, d1_g, d1_bt, d2pWt, d2_b, d2_g,
        d2_bt, dw_W, dw_b, pwWt, pw_b, sep_g, sep_bt, (float*)d_out);
}